// Round 3
// baseline (629.413 us; speedup 1.0000x reference)
//
#include <hip/hip_runtime.h>
#include <hip/hip_bf16.h>

// Problem constants (from reference)
#define N_IN    4096
#define N_OUT   4096
#define RANK    64
#define RES_RANK 4
#define RTOT    68      // RANK + RES_RANK
#define BATCH   8192

// ---------------------------------------------------------------------------
// Kernel A: split-K partial products  t_part[ks][r][b] = sum_{i in chunk ks}
//           Vcat[i][r] * x[i][b],  r in [0,68)  (first 64 from V, last 4 V_res)
// One thread per batch column; V row values are wave-uniform (scalar loads).
// ---------------------------------------------------------------------------
__global__ __launch_bounds__(256) void t_partial_kernel(
    const float* __restrict__ x,
    const float* __restrict__ V,
    const float* __restrict__ V_res,
    float* __restrict__ t_part,
    int kchunk)
{
    const int b  = blockIdx.x * 256 + threadIdx.x;   // batch column
    const int ks = blockIdx.y;                        // k-split index
    const int k0 = ks * kchunk;

    float acc[RTOT];
#pragma unroll
    for (int r = 0; r < RTOT; ++r) acc[r] = 0.0f;

    const float* xp = x + (size_t)k0 * BATCH + b;

#pragma unroll 2
    for (int i = 0; i < kchunk; ++i) {
        const float xv = xp[(size_t)i * BATCH];       // coalesced across lanes
        const float* vrow  = V     + (size_t)(k0 + i) * RANK;     // uniform
        const float* vrrow = V_res + (size_t)(k0 + i) * RES_RANK; // uniform
#pragma unroll
        for (int r = 0; r < RANK; ++r)
            acc[r] = fmaf(vrow[r], xv, acc[r]);
#pragma unroll
        for (int r = 0; r < RES_RANK; ++r)
            acc[RANK + r] = fmaf(vrrow[r], xv, acc[RANK + r]);
    }

    float* tp = t_part + (size_t)ks * (RTOT * BATCH) + b;
#pragma unroll
    for (int r = 0; r < RTOT; ++r)
        tp[(size_t)r * BATCH] = acc[r];
}

// ---------------------------------------------------------------------------
// Kernel A2: reduce split-K partials:  t[r][b] = sum_ks t_part[ks][r][b]
// ---------------------------------------------------------------------------
__global__ __launch_bounds__(256) void t_reduce_kernel(
    const float* __restrict__ t_part,
    float* __restrict__ t,
    int ksplit)
{
    const size_t idx = (size_t)blockIdx.x * 256 + threadIdx.x;  // over RTOT*BATCH
    float s = 0.0f;
    for (int k = 0; k < ksplit; ++k)
        s += t_part[(size_t)k * (RTOT * BATCH) + idx];
    t[idx] = s;
}

// ---------------------------------------------------------------------------
// Kernel B: out[o][b] = relu( sum_{r<64} U[o][r]*t[r][b]
//                           + sum_{r<4}  U_res[o][r]*t[64+r][b] )
// One thread per batch column, 64 output rows per block (t column reused).
// U row values are wave-uniform (scalar loads).
// ---------------------------------------------------------------------------
__global__ __launch_bounds__(256) void out_kernel(
    const float* __restrict__ t,
    const float* __restrict__ U,
    const float* __restrict__ U_res,
    float* __restrict__ out)
{
    const int b  = blockIdx.x * 256 + threadIdx.x;   // batch column
    const int o0 = blockIdx.y * 64;                  // output-row block

    float tcol[RTOT];
#pragma unroll
    for (int r = 0; r < RTOT; ++r)
        tcol[r] = t[(size_t)r * BATCH + b];          // coalesced across lanes

#pragma unroll 2
    for (int o = o0; o < o0 + 64; ++o) {
        const float* urow  = U     + (size_t)o * RANK;      // uniform
        const float* urrow = U_res + (size_t)o * RES_RANK;  // uniform
        // 4 partial sums to break the serial FMA dependency chain
        float s0 = 0.f, s1 = 0.f, s2 = 0.f, s3 = 0.f;
#pragma unroll
        for (int r = 0; r < RANK; r += 4) {
            s0 = fmaf(urow[r + 0], tcol[r + 0], s0);
            s1 = fmaf(urow[r + 1], tcol[r + 1], s1);
            s2 = fmaf(urow[r + 2], tcol[r + 2], s2);
            s3 = fmaf(urow[r + 3], tcol[r + 3], s3);
        }
        s0 = fmaf(urrow[0], tcol[RANK + 0], s0);
        s1 = fmaf(urrow[1], tcol[RANK + 1], s1);
        s2 = fmaf(urrow[2], tcol[RANK + 2], s2);
        s3 = fmaf(urrow[3], tcol[RANK + 3], s3);
        const float s = (s0 + s1) + (s2 + s3);
        out[(size_t)o * BATCH + b] = fmaxf(s, 0.0f);
    }
}

// ---------------------------------------------------------------------------
extern "C" void kernel_launch(void* const* d_in, const int* in_sizes, int n_in,
                              void* d_out, int out_size, void* d_ws, size_t ws_size,
                              hipStream_t stream)
{
    const float* x     = (const float*)d_in[0];   // (N_IN, BATCH)
    const float* U     = (const float*)d_in[1];   // (N_OUT, RANK)
    const float* V     = (const float*)d_in[2];   // (N_IN, RANK)
    const float* U_res = (const float*)d_in[3];   // (N_OUT, RES_RANK)
    const float* V_res = (const float*)d_in[4];   // (N_IN, RES_RANK)
    float* out = (float*)d_out;                   // (N_OUT, BATCH)

    // Workspace layout: [t_part: ksplit * RTOT * BATCH floats][t: RTOT * BATCH floats]
    const size_t t_elems = (size_t)RTOT * BATCH;   // 557056 floats = 2.2 MB
    int ksplit = 16;
    while (ksplit > 1 &&
           ws_size < (size_t)(ksplit + 1) * t_elems * sizeof(float))
        ksplit >>= 1;
    const int kchunk = N_IN / ksplit;

    float* t_part = (float*)d_ws;
    float* t      = t_part + (size_t)ksplit * t_elems;

    // A: partial t
    {
        dim3 grid(BATCH / 256, ksplit);
        t_partial_kernel<<<grid, 256, 0, stream>>>(x, V, V_res, t_part, kchunk);
    }
    // A2: reduce partials
    {
        dim3 grid((unsigned)(t_elems / 256));
        t_reduce_kernel<<<grid, 256, 0, stream>>>(t_part, t, ksplit);
    }
    // B: out = relu(Ucat @ t)
    {
        dim3 grid(BATCH / 256, N_OUT / 64);
        out_kernel<<<grid, 256, 0, stream>>>(t, U, U_res, out);
    }
}

// Round 10
// 262.032 us; speedup vs baseline: 2.4020x; 2.4020x over previous
//
#include <hip/hip_runtime.h>
#include <hip/hip_bf16.h>

#define N_IN    4096
#define N_OUT   4096
#define RANK    64
#define RES_RANK 4
#define RTOT    68      // RANK + RES_RANK
#define KPAD    96      // RTOT padded to 3 MFMA k-steps of 32
#define BATCH   8192

typedef short bf16x8 __attribute__((ext_vector_type(8)));   // MFMA A/B frag (4 VGPRs)
typedef float f32x4  __attribute__((ext_vector_type(4)));   // MFMA C/D frag
typedef float f32x2  __attribute__((ext_vector_type(2)));

__device__ inline short f2bf(float f) {
    __hip_bfloat16 h = __float2bfloat16(f);
    return *reinterpret_cast<short*>(&h);
}

// ---------------------------------------------------------------------------
// Phase A: t_part[ks][m][b] = sum_{k in chunk ks} Vcat[k][m] * x[k][b]
// Per block: M=80 (68 real, 12 zero-pad) x N=128, K=kchunk (512).
// MFMA 16x16x32 bf16; A = Vcat^T chunk (m x k), B = x chunk (k x n).
// ---------------------------------------------------------------------------
__global__ __launch_bounds__(256) void phaseA_kernel(
    const float* __restrict__ x,
    const float* __restrict__ V,
    const float* __restrict__ Vr,
    float* __restrict__ t_part,
    int kchunk)
{
    __shared__ __align__(16) float sA[32][82];   // [k][m], m 0..79 (68 real)
    __shared__ __align__(16) float sB[32][130];  // [k][n], n 0..127
    const int tid  = threadIdx.x;
    const int lane = tid & 63;
    const int wv   = tid >> 6;
    const int ln15 = lane & 15;
    const int g    = lane >> 4;
    const int b0   = blockIdx.x * 128;
    const int ks   = blockIdx.y;
    const int k0   = ks * kchunk;

    f32x4 acc[5][2];
#pragma unroll
    for (int mt = 0; mt < 5; ++mt)
#pragma unroll
        for (int u = 0; u < 2; ++u)
            acc[mt][u] = (f32x4)0.0f;

    // Zero the pad columns of sA (m = 68..81) once; never rewritten.
    for (int i = tid; i < 32 * 14; i += 256) {
        int k = i / 14, c = i % 14;
        sA[k][68 + c] = 0.0f;
    }

    for (int kk = 0; kk < kchunk; kk += 32) {
        __syncthreads();   // previous iteration's frag reads done (also fences zero-pass)

        // ---- stage V chunk: 32 rows x 64 f32 (rows contiguous in V) ----
        {
            int k = tid >> 3, i0 = (tid & 7) * 8;
            const float* src = V + (size_t)(k0 + kk + k) * RANK + i0;
            float4 v0 = *(const float4*)(src);
            float4 v1 = *(const float4*)(src + 4);
            *(f32x2*)&sA[k][i0 + 0] = f32x2{v0.x, v0.y};
            *(f32x2*)&sA[k][i0 + 2] = f32x2{v0.z, v0.w};
            *(f32x2*)&sA[k][i0 + 4] = f32x2{v1.x, v1.y};
            *(f32x2*)&sA[k][i0 + 6] = f32x2{v1.z, v1.w};
        }
        if (tid < 32) {
            float4 vr = *(const float4*)(Vr + (size_t)(k0 + kk + tid) * RES_RANK);
            *(f32x2*)&sA[tid][64] = f32x2{vr.x, vr.y};
            *(f32x2*)&sA[tid][66] = f32x2{vr.z, vr.w};
        }
        // ---- stage x chunk: 32 rows x 128 f32 ----
        {
            int kb  = lane >> 5;          // 0..1
            int col = (lane & 31) * 4;    // 0..124
#pragma unroll
            for (int c = 0; c < 4; ++c) {
                int k = wv * 8 + c * 2 + kb;
                float4 v = *(const float4*)(x + (size_t)(k0 + kk + k) * BATCH + b0 + col);
                *(f32x2*)&sB[k][col + 0] = f32x2{v.x, v.y};
                *(f32x2*)&sB[k][col + 2] = f32x2{v.z, v.w};
            }
        }
        __syncthreads();

        // ---- fragments (A[m][k] = sA[k][m], B[k][n] = sB[k][n]) ----
        bf16x8 af[5], bfr[2];
#pragma unroll
        for (int mt = 0; mt < 5; ++mt) {
            int m = mt * 16 + ln15;
#pragma unroll
            for (int j = 0; j < 8; ++j)
                af[mt][j] = f2bf(sA[g * 8 + j][m]);
        }
#pragma unroll
        for (int u = 0; u < 2; ++u) {
            int n = (wv * 2 + u) * 16 + ln15;
#pragma unroll
            for (int j = 0; j < 8; ++j)
                bfr[u][j] = f2bf(sB[g * 8 + j][n]);
        }
#pragma unroll
        for (int mt = 0; mt < 5; ++mt)
#pragma unroll
            for (int u = 0; u < 2; ++u)
                acc[mt][u] = __builtin_amdgcn_mfma_f32_16x16x32_bf16(
                    af[mt], bfr[u], acc[mt][u], 0, 0, 0);
    }

    // ---- epilogue: partial t (f32), rows m < 68 only ----
#pragma unroll
    for (int mt = 0; mt < 5; ++mt)
#pragma unroll
        for (int u = 0; u < 2; ++u)
#pragma unroll
            for (int r = 0; r < 4; ++r) {
                int m = mt * 16 + g * 4 + r;        // C/D: row=(lane>>4)*4+reg
                if (m < RTOT) {
                    size_t off = ((size_t)ks * RTOT + m) * BATCH
                               + b0 + (wv * 2 + u) * 16 + ln15;  // col=lane&15
                    t_part[off] = acc[mt][u][r];
                }
            }
}

// ---------------------------------------------------------------------------
// Reduce: t_bf16[b][k] = bf16( sum_ks t_part[ks][k][b] ), k<68; zeros k=68..95.
// Writes t TRANSPOSED (b-major) so phase B stages B-tiles with dense row copies.
// ---------------------------------------------------------------------------
__global__ __launch_bounds__(256) void reduce_kernel(
    const float* __restrict__ t_part,
    unsigned short* __restrict__ t_bf16,
    int ksplit)
{
    __shared__ __align__(16) unsigned short sT[32][104];
    const int tid = threadIdx.x;
    const int b0  = blockIdx.x * 32;

    // zero sT (covers k = 68..95 and pads)
    for (int i = tid; i < (32 * 104 * 2) / 16; i += 256)
        ((uint4*)sT)[i] = uint4{0, 0, 0, 0};
    __syncthreads();

    {
        int b  = tid & 31;
        int rq = tid >> 5;            // 8 groups x 9 rows = 72 >= 68
        if (ksplit == 8) {
#pragma unroll 1
            for (int i = 0; i < 9; ++i) {
                int r = rq * 9 + i;
                if (r < RTOT) {
                    float s = 0.f;
#pragma unroll
                    for (int k = 0; k < 8; ++k)
                        s += t_part[((size_t)k * RTOT + r) * BATCH + b0 + b];
                    sT[b][r] = (unsigned short)f2bf(s);
                }
            }
        } else {
#pragma unroll 1
            for (int i = 0; i < 9; ++i) {
                int r = rq * 9 + i;
                if (r < RTOT) {
                    float s = 0.f;
                    for (int k = 0; k < ksplit; ++k)
                        s += t_part[((size_t)k * RTOT + r) * BATCH + b0 + b];
                    sT[b][r] = (unsigned short)f2bf(s);
                }
            }
        }
    }
    __syncthreads();

    // write rows: 32 rows x 12 uint4 chunks (96 bf16 per row)
    {
        int b = tid >> 3, c = tid & 7;
        uint4 v = *(const uint4*)&sT[b][c * 8];
        *(uint4*)(t_bf16 + (size_t)(b0 + b) * KPAD + c * 8) = v;
        if (c < 4) {
            uint4 v2 = *(const uint4*)&sT[b][(c + 8) * 8];
            *(uint4*)(t_bf16 + (size_t)(b0 + b) * KPAD + (c + 8) * 8) = v2;
        }
    }
}

// ---------------------------------------------------------------------------
// Phase B: out = relu(Ucat @ t). Per block 128(M) x 128(N), K = 96 (3 steps).
// All frag loads are aligned ds_read_b128 from [row][104]-strided bf16 tiles.
// ---------------------------------------------------------------------------
__global__ __launch_bounds__(256) void phaseB_kernel(
    const unsigned short* __restrict__ t_bf16,
    const float* __restrict__ U,
    const float* __restrict__ Ur,
    float* __restrict__ out)
{
    __shared__ __align__(16) unsigned short sU[128][104];  // [m][k]
    __shared__ __align__(16) unsigned short sT[128][104];  // [n][k]
    const int tid  = threadIdx.x;
    const int lane = tid & 63;
    const int wv   = tid >> 6;
    const int ln15 = lane & 15;
    const int g    = lane >> 4;
    const int b0   = blockIdx.x * 128;   // batch offset
    const int m0   = blockIdx.y * 128;   // out-row offset

    // ---- stage U (f32 -> bf16), plus U_res and zero pad k=68..95 ----
    {
        int m = tid >> 1, h = tid & 1;
        const float* src = U + (size_t)(m0 + m) * RANK + h * 32;
#pragma unroll
        for (int c = 0; c < 8; ++c) {
            float4 v = *(const float4*)(src + c * 4);
            union { unsigned short us[4]; uint2 u2; } p;
            p.us[0] = (unsigned short)f2bf(v.x);
            p.us[1] = (unsigned short)f2bf(v.y);
            p.us[2] = (unsigned short)f2bf(v.z);
            p.us[3] = (unsigned short)f2bf(v.w);
            *(uint2*)&sU[m][h * 32 + c * 4] = p.u2;
        }
    }
    if (tid < 128) {
        int m = tid;
        float4 v = *(const float4*)(Ur + (size_t)(m0 + m) * RES_RANK);
        union { unsigned short us[4]; uint2 u2; } p;
        p.us[0] = (unsigned short)f2bf(v.x);
        p.us[1] = (unsigned short)f2bf(v.y);
        p.us[2] = (unsigned short)f2bf(v.z);
        p.us[3] = (unsigned short)f2bf(v.w);
        *(uint2*)&sU[m][64] = p.u2;
        uint2 z{0, 0};
#pragma unroll
        for (int c = 0; c < 7; ++c)
            *(uint2*)&sU[m][68 + c * 4] = z;
    }
    // ---- stage t tile: dense bf16 row copies ----
    {
        int n = tid >> 1, c6 = (tid & 1) * 6;
        const unsigned short* src = t_bf16 + (size_t)(b0 + n) * KPAD + c6 * 8;
#pragma unroll
        for (int i = 0; i < 6; ++i) {
            uint4 v = *(const uint4*)(src + i * 8);
            *(uint4*)&sT[n][(c6 + i) * 8] = v;
        }
    }
    __syncthreads();

    // ---- MFMA: per wave 2 m-tiles x 8 n-tiles, K = 96 ----
    f32x4 acc[2][8];
#pragma unroll
    for (int q = 0; q < 2; ++q)
#pragma unroll
        for (int nt = 0; nt < 8; ++nt)
            acc[q][nt] = (f32x4)0.0f;

#pragma unroll
    for (int ks = 0; ks < 3; ++ks) {
        bf16x8 a[2], b[8];
#pragma unroll
        for (int q = 0; q < 2; ++q) {
            int m = (wv * 2 + q) * 16 + ln15;
            a[q] = *(const bf16x8*)&sU[m][ks * 32 + g * 8];
        }
#pragma unroll
        for (int nt = 0; nt < 8; ++nt) {
            int n = nt * 16 + ln15;
            b[nt] = *(const bf16x8*)&sT[n][ks * 32 + g * 8];
        }
#pragma unroll
        for (int q = 0; q < 2; ++q)
#pragma unroll
            for (int nt = 0; nt < 8; ++nt)
                acc[q][nt] = __builtin_amdgcn_mfma_f32_16x16x32_bf16(
                    a[q], b[nt], acc[q][nt], 0, 0, 0);
    }

    // ---- epilogue: relu + f32 store ----
#pragma unroll
    for (int q = 0; q < 2; ++q)
#pragma unroll
        for (int nt = 0; nt < 8; ++nt)
#pragma unroll
            for (int r = 0; r < 4; ++r) {
                int row = m0 + (wv * 2 + q) * 16 + g * 4 + r;
                int col = b0 + nt * 16 + ln15;
                out[(size_t)row * BATCH + col] = fmaxf(acc[q][nt][r], 0.0f);
            }
}

// ---------------------------------------------------------------------------
extern "C" void kernel_launch(void* const* d_in, const int* in_sizes, int n_in,
                              void* d_out, int out_size, void* d_ws, size_t ws_size,
                              hipStream_t stream)
{
    const float* x  = (const float*)d_in[0];   // (N_IN, BATCH)
    const float* U  = (const float*)d_in[1];   // (N_OUT, RANK)
    const float* V  = (const float*)d_in[2];   // (N_IN, RANK)
    const float* Ur = (const float*)d_in[3];   // (N_OUT, RES_RANK)
    const float* Vr = (const float*)d_in[4];   // (N_IN, RES_RANK)
    float* out = (float*)d_out;                // (N_OUT, BATCH)

    int ksplit = 8;
    while (ksplit > 1 &&
           ws_size < (size_t)ksplit * RTOT * BATCH * 4 + (size_t)BATCH * KPAD * 2)
        ksplit >>= 1;
    const int kchunk = N_IN / ksplit;

    float* t_part = (float*)d_ws;
    unsigned short* t_bf16 =
        (unsigned short*)((char*)d_ws + (size_t)ksplit * RTOT * BATCH * 4);

    phaseA_kernel<<<dim3(BATCH / 128, ksplit), 256, 0, stream>>>(x, V, Vr, t_part, kchunk);
    reduce_kernel<<<dim3(BATCH / 32), 256, 0, stream>>>(t_part, t_bf16, ksplit);
    phaseB_kernel<<<dim3(BATCH / 128, N_OUT / 128), 256, 0, stream>>>(t_bf16, U, Ur, out);
}